// Round 2
// baseline (188.391 us; speedup 1.0000x reference)
//
#include <hip/hip_runtime.h>

#define HH 128
#define WW 128
#define NPX (HH * WW)
#define KK 10
#define SEGS 16

// PP[2g]   = (a, 2b, c, mean_x)
// PP[2g+1] = (mean_y, r, g, b)
__device__ __forceinline__ float eval_alpha(const float4 q0, const float my,
                                            const float px, const float py) {
  float dx = px - q0.w;
  float dy = py - my;
  float q = fmaf(dx, fmaf(q0.y, dy, q0.x * dx), q0.z * dy * dy);
  return __expf(-0.5f * q);
}

__device__ __forceinline__ void compute_params(
    const float* __restrict__ means, const float* __restrict__ rots,
    const float* __restrict__ lscales, const float* __restrict__ cols,
    int g, float4* p0, float4* p1) {
  float mx = means[2 * g], my = means[2 * g + 1];
  float th = rots[g];
  float s = __sinf(th), c = __cosf(th);
  float ivx = __expf(-2.0f * lscales[2 * g]);
  float ivy = __expf(-2.0f * lscales[2 * g + 1]);
  float a  = c * c * ivx + s * s * ivy;
  float cc = s * s * ivx + c * c * ivy;
  float b2 = 2.0f * (c * s * (ivx - ivy));
  *p0 = make_float4(a, b2, cc, mx);
  *p1 = make_float4(my, cols[3 * g], cols[3 * g + 1], cols[3 * g + 2]);
}

__global__ void params_kernel(const float* __restrict__ means,
                              const float* __restrict__ rots,
                              const float* __restrict__ lscales,
                              const float* __restrict__ cols,
                              int nG, float4* __restrict__ PP) {
  int g = blockIdx.x * blockDim.x + threadIdx.x;
  if (g >= nG) return;
  float4 p0, p1;
  compute_params(means, rots, lscales, cols, g, &p0, &p1);
  PP[2 * g]     = p0;
  PP[2 * g + 1] = p1;
}

// Sorted descending insert; strict > preserves lower-index-first tie-break
// when inserted in ascending global-index order (matches jax.lax.top_k).
__device__ __forceinline__ void bubble_insert(float vals[KK], int ids[KK],
                                              float v, int vi) {
#pragma unroll
  for (int k = 0; k < KK; ++k) {
    bool sw = v > vals[k];
    float tv = vals[k];
    int ti = ids[k];
    vals[k] = sw ? v : tv;
    ids[k]  = sw ? vi : ti;
    v  = sw ? tv : v;
    vi = sw ? ti : vi;
  }
}

__device__ __forceinline__ void bubble_vals(float vals[KK], float v) {
#pragma unroll
  for (int k = 0; k < KK; ++k) {
    float tv = vals[k];
    bool sw = v > tv;
    vals[k] = sw ? v : tv;
    v = sw ? tv : v;
  }
}

// tau prepass: per-pixel 10th-largest alpha over a 256-gaussian strided
// sample. This is a sound LOWER BOUND on the global 10th-largest (a subset's
// k-th max <= full set's k-th max), so skipping alpha < tau in the segment
// phase is exact; ties (alpha == tau) are kept.
__global__ __launch_bounds__(64) void tau_kernel(const float4* __restrict__ PP,
                                                 int nG,
                                                 float* __restrict__ tau) {
  int p = blockIdx.x * 64 + threadIdx.x;
  int x = p & (WW - 1), y = p >> 7;
  float px = (float)x + 0.5f, py = (float)y + 0.5f;
  int sample = nG < 256 ? nG : 256;
  int stride = nG / sample;
  float vals[KK];
#pragma unroll
  for (int k = 0; k < KK; ++k) vals[k] = -1.0f;
  for (int i = 0; i < sample; ++i) {
    int g = i * stride;
    float4 q0 = PP[2 * g];                      // uniform -> scalar load
    float my = ((const float*)PP)[8 * g + 4];
    float a = eval_alpha(q0, my, px, py);
    if (a > vals[KK - 1]) bubble_vals(vals, a);
  }
  tau[p] = vals[KK - 1];
}

// Kernel: per-(pixel, segment) gated top-10. Grid (64 tiles, SEGS), 256 thr.
// No LDS: params come in via uniform (scalar) loads of PP.
__global__ __launch_bounds__(256) void topk_seg_kernel(
    const float4* __restrict__ PP, const float* __restrict__ tau, int Gseg,
    float* __restrict__ alphaBuf, int* __restrict__ idxBuf) {
  int tile = blockIdx.x, seg = blockIdx.y, t = threadIdx.x;
  int x = ((tile & 7) << 4) | (t & 15);
  int y = ((tile >> 3) << 4) | (t >> 4);
  int p = y * WW + x;
  float px = (float)x + 0.5f, py = (float)y + 0.5f;
  float tv = tau[p];
  int g0 = seg * Gseg;

  float vals[KK];
  int ids[KK];
#pragma unroll
  for (int k = 0; k < KK; ++k) { vals[k] = -1.0f; ids[k] = 0; }

  for (int i = 0; i < Gseg; ++i) {
    int g = g0 + i;
    float4 q0 = PP[2 * g];                      // uniform -> scalar load
    float my = ((const float*)PP)[8 * g + 4];
    float a = eval_alpha(q0, my, px, py);
    if (a >= tv && a > vals[KK - 1]) bubble_insert(vals, ids, a, g);
  }

  // [pixel][seg][k] layout; per-lane contiguous 40B, float2-vectorized.
  float* ab = alphaBuf + (size_t)p * (SEGS * KK) + seg * KK;
  int*   ib = idxBuf  + (size_t)p * (SEGS * KK) + seg * KK;
#pragma unroll
  for (int k = 0; k < KK; k += 2) {
    *(float2*)(ab + k) = make_float2(vals[k], vals[k + 1]);
    *(int2*)(ib + k)   = make_int2(ids[k], ids[k + 1]);
  }
}

// Merge: 2 lanes per pixel (lane parity = segment half). Unconditional
// vectorized loads (pipelined), register-only break tests, shfl combine.
__global__ __launch_bounds__(256) void merge_kernel(
    const float* __restrict__ alphaBuf, const int* __restrict__ idxBuf,
    const float4* __restrict__ PP, float* __restrict__ out) {
  int gt = blockIdx.x * 256 + threadIdx.x;
  int p = gt >> 1, half = gt & 1;
  const float* ab = alphaBuf + (size_t)p * (SEGS * KK) + half * (8 * KK);
  const int*   ib = idxBuf  + (size_t)p * (SEGS * KK) + half * (8 * KK);

  float vals[KK];
  int ids[KK];
#pragma unroll
  for (int k = 0; k < KK; ++k) { vals[k] = -1.0f; ids[k] = 0; }

  for (int pr = 0; pr < 4; ++pr) {  // two segments per iteration (80B, 16B-aligned)
    float a20[2 * KK];
    int   i20[2 * KK];
    const float4* a4 = (const float4*)(ab + pr * 2 * KK);
    const int4*   i4 = (const int4*)(ib + pr * 2 * KK);
#pragma unroll
    for (int j = 0; j < 5; ++j) {
      float4 av = a4[j];
      int4   iv = i4[j];
      a20[4 * j + 0] = av.x; a20[4 * j + 1] = av.y;
      a20[4 * j + 2] = av.z; a20[4 * j + 3] = av.w;
      i20[4 * j + 0] = iv.x; i20[4 * j + 1] = iv.y;
      i20[4 * j + 2] = iv.z; i20[4 * j + 3] = iv.w;
    }
#pragma unroll
    for (int k = 0; k < KK; ++k) {      // segment 2*pr (descending list)
      float a = a20[k];
      if (!(a > vals[KK - 1])) break;
      bubble_insert(vals, ids, a, i20[k]);
    }
#pragma unroll
    for (int k = KK; k < 2 * KK; ++k) { // segment 2*pr+1
      float a = a20[k];
      if (!(a > vals[KK - 1])) break;
      bubble_insert(vals, ids, a, i20[k]);
    }
  }

  // Cross-half combine: half1 (higher gaussian indices) loses ties via strict >.
  float ov[KK];
  int oi[KK];
#pragma unroll
  for (int k = 0; k < KK; ++k) {
    ov[k] = __shfl_xor(vals[k], 1);
    oi[k] = __shfl_xor(ids[k], 1);
  }
  if (half == 0) {
#pragma unroll
    for (int k = 0; k < KK; ++k) {
      float a = ov[k];
      if (!(a > vals[KK - 1])) break;
      bubble_insert(vals, ids, a, oi[k]);
    }
    float trans = 1.0f, r = 0.0f, g = 0.0f, b = 0.0f;
#pragma unroll
    for (int k = 0; k < KK; ++k) {
      float a = vals[k];
      float w = a * trans;
      float4 q1 = PP[2 * ids[k] + 1];
      r += w * q1.y;
      g += w * q1.z;
      b += w * q1.w;
      trans *= (1.0f - a);
    }
    out[3 * p + 0] = r;
    out[3 * p + 1] = g;
    out[3 * p + 2] = b;
  }
}

// Fallback: monolithic (no workspace needed).
__global__ __launch_bounds__(256) void mono_kernel(
    const float* __restrict__ means, const float* __restrict__ rots,
    const float* __restrict__ lscales, const float* __restrict__ cols,
    int nG, float* __restrict__ out) {
  int tile = blockIdx.x;
  int t = threadIdx.x;
  int x = ((tile & 7) << 4) | (t & 15);
  int y = ((tile >> 3) << 4) | (t >> 4);
  int p = y * WW + x;
  float px = (float)x + 0.5f, py = (float)y + 0.5f;

  __shared__ float4 lds[512];

  float vals[KK];
  int ids[KK];
#pragma unroll
  for (int k = 0; k < KK; ++k) { vals[k] = -1.0f; ids[k] = 0; }

  for (int c0 = 0; c0 < nG; c0 += 256) {
    int nchunk = min(256, nG - c0);
    __syncthreads();
    if (t < nchunk) {
      float4 p0, p1;
      compute_params(means, rots, lscales, cols, c0 + t, &p0, &p1);
      lds[2 * t] = p0;
      lds[2 * t + 1] = p1;
    }
    __syncthreads();
    for (int gg = 0; gg < nchunk; ++gg) {
      float4 q0 = lds[2 * gg];
      float4 q1 = lds[2 * gg + 1];
      float a = eval_alpha(q0, q1.x, px, py);
      if (a > vals[KK - 1]) bubble_insert(vals, ids, a, c0 + gg);
    }
  }

  float trans = 1.0f, r = 0.0f, g = 0.0f, b = 0.0f;
#pragma unroll
  for (int k = 0; k < KK; ++k) {
    float a = vals[k];
    float w = a * trans;
    int i = ids[k];
    r += w * cols[3 * i + 0];
    g += w * cols[3 * i + 1];
    b += w * cols[3 * i + 2];
    trans *= (1.0f - a);
  }
  out[3 * p + 0] = r;
  out[3 * p + 1] = g;
  out[3 * p + 2] = b;
}

extern "C" void kernel_launch(void* const* d_in, const int* in_sizes, int n_in,
                              void* d_out, int out_size, void* d_ws, size_t ws_size,
                              hipStream_t stream) {
  const float* means   = (const float*)d_in[0];
  const float* rots    = (const float*)d_in[1];
  const float* lscales = (const float*)d_in[2];
  const float* cols    = (const float*)d_in[3];
  float* out = (float*)d_out;
  int nG = in_sizes[1];  // rotations: one per gaussian

  // ws layout: [alphaBuf f32 NPX*SEGS*KK][idxBuf i32 same][PP 2*nG float4][tau f32 NPX]
  size_t szA  = (size_t)NPX * SEGS * KK * 4;
  size_t need = 2 * szA + (size_t)nG * 32 + (size_t)NPX * 4;
  bool seg_ok = (need <= ws_size) && (nG % SEGS == 0) && (nG / SEGS >= KK);

  if (seg_ok) {
    float*  alphaBuf = (float*)d_ws;
    int*    idxBuf   = (int*)((char*)d_ws + szA);
    float4* PP       = (float4*)((char*)d_ws + 2 * szA);
    float*  tau      = (float*)((char*)d_ws + 2 * szA + (size_t)nG * 32);
    params_kernel<<<(nG + 255) / 256, 256, 0, stream>>>(means, rots, lscales, cols, nG, PP);
    tau_kernel<<<NPX / 64, 64, 0, stream>>>(PP, nG, tau);
    topk_seg_kernel<<<dim3(NPX / 256, SEGS), 256, 0, stream>>>(PP, tau, nG / SEGS, alphaBuf, idxBuf);
    merge_kernel<<<NPX * 2 / 256, 256, 0, stream>>>(alphaBuf, idxBuf, PP, out);
  } else {
    mono_kernel<<<NPX / 256, 256, 0, stream>>>(means, rots, lscales, cols, nG, out);
  }
}

// Round 3
// 98.337 us; speedup vs baseline: 1.9158x; 1.9158x over previous
//
#include <hip/hip_runtime.h>

#define HH 128
#define WW 128
#define NPX (HH * WW)
#define KK 10
#define PXB 16      // pixels per block (4x4 tile)
#define TPP 16      // threads per pixel
#define CHUNK 256   // gaussians staged per chunk
#define CAP 257     // survivor slots per pixel (256 usable; 257 stride -> 2-way banks only)

// PA[g] = (a, 2b, c, mean_x);  PMy[g] = mean_y;  PC[g] = (r, g, b, 0)
__device__ __forceinline__ float eval_alpha(const float4 q0, const float my,
                                            const float px, const float py) {
  float dx = px - q0.w;
  float dy = py - my;
  float q = fmaf(dx, fmaf(q0.y, dy, q0.x * dx), q0.z * dy * dy);
  return __expf(-0.5f * q);
}

__device__ __forceinline__ void compute_params(
    const float* __restrict__ means, const float* __restrict__ rots,
    const float* __restrict__ lscales, const float* __restrict__ cols,
    int g, float4* p0, float* pmy, float4* pc) {
  float mx = means[2 * g], my = means[2 * g + 1];
  float th = rots[g];
  float s = __sinf(th), c = __cosf(th);
  float ivx = __expf(-2.0f * lscales[2 * g]);
  float ivy = __expf(-2.0f * lscales[2 * g + 1]);
  float a  = c * c * ivx + s * s * ivy;
  float cc = s * s * ivx + c * c * ivy;
  float b2 = 2.0f * (c * s * (ivx - ivy));
  *p0 = make_float4(a, b2, cc, mx);
  *pmy = my;
  *pc = make_float4(cols[3 * g], cols[3 * g + 1], cols[3 * g + 2], 0.0f);
}

__global__ void params_kernel(const float* __restrict__ means,
                              const float* __restrict__ rots,
                              const float* __restrict__ lscales,
                              const float* __restrict__ cols, int nG,
                              float4* __restrict__ PA, float* __restrict__ PMy,
                              float4* __restrict__ PC) {
  int g = blockIdx.x * blockDim.x + threadIdx.x;
  if (g >= nG) return;
  float4 p0, pc;
  float my;
  compute_params(means, rots, lscales, cols, g, &p0, &my, &pc);
  PA[g] = p0;
  PMy[g] = my;
  PC[g] = pc;
}

// Descending top-10 of values only (no ids) — used for the tau bound.
__device__ __forceinline__ void bubble_vals10(float vals[KK], float v) {
#pragma unroll
  for (int k = 0; k < KK; ++k) {
    float tv = vals[k];
    bool sw = v > tv;
    vals[k] = sw ? v : tv;
    v = sw ? tv : v;
  }
}

// Lexicographic (alpha desc, id asc) — exact jax.lax.top_k tie semantics.
__device__ __forceinline__ bool beats(float a, int ai, float b, int bi) {
  return (a > b) || (a == b && ai < bi);
}

__device__ __forceinline__ void insert_tb(float vals[KK], int ids[KK], float v,
                                          int vi) {
#pragma unroll
  for (int k = 0; k < KK; ++k) {
    bool sw = beats(v, vi, vals[k], ids[k]);
    float tv = vals[k];
    int ti = ids[k];
    vals[k] = sw ? v : tv;
    ids[k]  = sw ? vi : ti;
    v  = sw ? tv : v;
    vi = sw ? ti : vi;
  }
}

__global__ __launch_bounds__(256) void fused_kernel(
    const float4* __restrict__ PA, const float* __restrict__ PMy,
    const float4* __restrict__ PC, int nG, float* __restrict__ out) {
  __shared__ float4 cA[CHUNK];
  __shared__ float  cMy[CHUNK];
  __shared__ float  smax[TPP * PXB];
  __shared__ int    scnt[PXB];
  __shared__ float2 sbuf[PXB][CAP];

  int t  = threadIdx.x;
  int pl = t & 15;   // pixel within block
  int ts = t >> 4;   // thread-segment 0..15 (gaussians g == ts mod 16 of chunk)
  int tile = blockIdx.x;                 // 32x32 tiles of 4x4 pixels
  int x = ((tile & 31) << 2) | (pl & 3);
  int y = ((tile >> 5) << 2) | (pl >> 2);
  int p = y * WW + x;
  float px = (float)x + 0.5f, py = (float)y + 0.5f;

  // ---- stage chunk 0 + init counters ----
  cA[t]  = PA[t];
  cMy[t] = PMy[t];
  if (t < PXB) scnt[t] = 0;
  __syncthreads();

  // ---- phase 1: per-thread max over its 16 samples of chunk 0 ----
  float mx = 0.0f;
#pragma unroll
  for (int j = 0; j < CHUNK / TPP; ++j) {
    int gi = j * 16 + ts;
    mx = fmaxf(mx, eval_alpha(cA[gi], cMy[gi], px, py));
  }
  smax[ts * PXB + pl] = mx;
  __syncthreads();

  // tau = 10th largest of the 16 per-thread maxes (a subset of all alphas,
  // hence a sound lower bound on the global 10th), floored at 5e-4
  // (dropping alpha<5e-4 items perturbs the output by <= 10*5e-4 << 2e-2).
  float tvals[KK];
#pragma unroll
  for (int k = 0; k < KK; ++k) tvals[k] = 0.0f;
#pragma unroll
  for (int i = 0; i < TPP; ++i) bubble_vals10(tvals, smax[i * PXB + pl]);
  float tau = fmaxf(tvals[KK - 1], 5e-4f);

  // ---- phase 2: scan all gaussians, push survivors (alpha >= tau) ----
  for (int c0 = 0; c0 < nG; c0 += CHUNK) {
    if (c0 > 0) {
      __syncthreads();
      cA[t]  = PA[c0 + t];
      cMy[t] = PMy[c0 + t];
      __syncthreads();
    }
#pragma unroll 4
    for (int j = 0; j < CHUNK / TPP; ++j) {
      int gi = j * 16 + ts;
      float a = eval_alpha(cA[gi], cMy[gi], px, py);
      if (a >= tau) {
        int idx = atomicAdd(&scnt[pl], 1);
        if (idx < CAP - 1)
          sbuf[pl][idx] = make_float2(a, __int_as_float(c0 + gi));
      }
    }
  }
  __syncthreads();

  // ---- phase 3: 2 lanes per pixel select exact top-10 + composite ----
  if (t < 2 * PXB) {
    int p2 = t >> 1, half = t & 1;
    int cnt = min(scnt[p2], CAP - 1);
    float vals[KK];
    int ids[KK];
#pragma unroll
    for (int k = 0; k < KK; ++k) { vals[k] = 0.0f; ids[k] = 0; }
    for (int i = half; i < cnt; i += 2) {
      float2 e = sbuf[p2][i];
      float a = e.x;
      int id = __float_as_int(e.y);
      if (beats(a, id, vals[KK - 1], ids[KK - 1])) insert_tb(vals, ids, a, id);
    }
    // combine the two halves (shfl over lane pair)
    float ov[KK];
    int oi[KK];
#pragma unroll
    for (int k = 0; k < KK; ++k) {
      ov[k] = __shfl_xor(vals[k], 1);
      oi[k] = __shfl_xor(ids[k], 1);
    }
    if (half == 0) {
#pragma unroll
      for (int k = 0; k < KK; ++k) {
        if (!beats(ov[k], oi[k], vals[KK - 1], ids[KK - 1])) break;
        insert_tb(vals, ids, ov[k], oi[k]);
      }
      int px2 = ((tile & 31) << 2) | (p2 & 3);
      int py2 = ((tile >> 5) << 2) | (p2 >> 2);
      int pp = py2 * WW + px2;
      float trans = 1.0f, r = 0.0f, g = 0.0f, b = 0.0f;
#pragma unroll
      for (int k = 0; k < KK; ++k) {
        float a = vals[k];           // sentinel 0.0 contributes nothing
        float w = a * trans;
        float4 c = PC[ids[k]];
        r += w * c.x;
        g += w * c.y;
        b += w * c.z;
        trans *= (1.0f - a);
      }
      out[3 * pp + 0] = r;
      out[3 * pp + 1] = g;
      out[3 * pp + 2] = b;
    }
  }
}

// Fallback: monolithic, exact, no workspace assumptions (odd nG etc).
__global__ __launch_bounds__(256) void mono_kernel(
    const float* __restrict__ means, const float* __restrict__ rots,
    const float* __restrict__ lscales, const float* __restrict__ cols, int nG,
    float* __restrict__ out) {
  int tile = blockIdx.x;
  int t = threadIdx.x;
  int x = ((tile & 7) << 4) | (t & 15);
  int y = ((tile >> 3) << 4) | (t >> 4);
  int p = y * WW + x;
  float px = (float)x + 0.5f, py = (float)y + 0.5f;

  __shared__ float4 lds[512];

  float vals[KK];
  int ids[KK];
#pragma unroll
  for (int k = 0; k < KK; ++k) { vals[k] = 0.0f; ids[k] = 0; }

  for (int c0 = 0; c0 < nG; c0 += 256) {
    int nchunk = min(256, nG - c0);
    __syncthreads();
    if (t < nchunk) {
      float4 p0, pc;
      float my;
      compute_params(means, rots, lscales, cols, c0 + t, &p0, &my, &pc);
      lds[2 * t] = p0;
      lds[2 * t + 1] = make_float4(my, pc.x, pc.y, pc.z);
    }
    __syncthreads();
    for (int gg = 0; gg < nchunk; ++gg) {
      float4 q0 = lds[2 * gg];
      float a = eval_alpha(q0, lds[2 * gg + 1].x, px, py);
      if (a > vals[KK - 1]) insert_tb(vals, ids, a, c0 + gg);
    }
  }

  float trans = 1.0f, r = 0.0f, g = 0.0f, b = 0.0f;
#pragma unroll
  for (int k = 0; k < KK; ++k) {
    float a = vals[k];
    float w = a * trans;
    int i = ids[k];
    r += w * cols[3 * i + 0];
    g += w * cols[3 * i + 1];
    b += w * cols[3 * i + 2];
    trans *= (1.0f - a);
  }
  out[3 * p + 0] = r;
  out[3 * p + 1] = g;
  out[3 * p + 2] = b;
}

extern "C" void kernel_launch(void* const* d_in, const int* in_sizes, int n_in,
                              void* d_out, int out_size, void* d_ws, size_t ws_size,
                              hipStream_t stream) {
  const float* means   = (const float*)d_in[0];
  const float* rots    = (const float*)d_in[1];
  const float* lscales = (const float*)d_in[2];
  const float* cols    = (const float*)d_in[3];
  float* out = (float*)d_out;
  int nG = in_sizes[1];  // rotations: one per gaussian

  // ws layout: [PA float4 nG][PC float4 nG][PMy float nG]
  size_t need = (size_t)nG * (16 + 16 + 4);
  bool ok = (nG % CHUNK == 0) && (nG >= CHUNK) && (need <= ws_size);

  if (ok) {
    float4* PA  = (float4*)d_ws;
    float4* PC  = (float4*)((char*)d_ws + (size_t)nG * 16);
    float*  PMy = (float*)((char*)d_ws + (size_t)nG * 32);
    params_kernel<<<(nG + 255) / 256, 256, 0, stream>>>(means, rots, lscales,
                                                        cols, nG, PA, PMy, PC);
    fused_kernel<<<NPX / PXB, 256, 0, stream>>>(PA, PMy, PC, nG, out);
  } else {
    mono_kernel<<<NPX / 256, 256, 0, stream>>>(means, rots, lscales, cols, nG, out);
  }
}

// Round 4
// 84.271 us; speedup vs baseline: 2.2355x; 1.1669x over previous
//
#include <hip/hip_runtime.h>

#define HH 128
#define WW 128
#define NPX (HH * WW)
#define KK 10
#define PXB 16        // pixels per block (4x4 tile)
#define TPP 16        // threads per pixel
#define LCAP 352      // per-tile gaussian list cap (expected ~126)
#define SCAP 176      // per-pixel survivor cap (expected ~60)
#define SPAD 177      // sbuf row stride: 177*8B -> row-to-row bank shift of 2
#define ALPHA_MIN 5e-4f
#define RADIUS_K 3.8990f  // sqrt(2*ln(1/ALPHA_MIN))

// Lexicographic (alpha desc, id asc) — exact jax.lax.top_k tie semantics,
// independent of candidate arrival order.
__device__ __forceinline__ bool beats(float a, int ai, float b, int bi) {
  return (a > b) || (a == b && ai < bi);
}

__device__ __forceinline__ void insert_tb(float vals[KK], int ids[KK], float v,
                                          int vi) {
#pragma unroll
  for (int k = 0; k < KK; ++k) {
    bool sw = beats(v, vi, vals[k], ids[k]);
    float tv = vals[k];
    int ti = ids[k];
    vals[k] = sw ? v : tv;
    ids[k]  = sw ? vi : ti;
    v  = sw ? tv : v;
    vi = sw ? ti : vi;
  }
}

// One block = one 4x4-pixel tile. 256 threads: filter all gaussians by a
// conservative bbox (circle containing the alpha>=ALPHA_MIN contour), compute
// full params for survivors only, eval 16 threads/pixel, exact top-10 select.
__global__ __launch_bounds__(256) void splat_kernel(
    const float* __restrict__ means, const float* __restrict__ rots,
    const float* __restrict__ lscales, const float* __restrict__ cols,
    int nG, float* __restrict__ out) {
  __shared__ float4 sA[LCAP];          // (a, 2b, c, mean_x)
  __shared__ float  sMy[LCAP];
  __shared__ int    glist[LCAP];
  __shared__ float2 sbuf[PXB][SPAD];   // (alpha, id-bits); padded stride
  __shared__ int    scnt[PXB];
  __shared__ int    lcnt;

  int t  = threadIdx.x;
  int pl = t & 15;   // pixel within tile
  int ts = t >> 4;   // per-pixel thread slot 0..15
  int tile = blockIdx.x;               // 32x32 tiles of 4x4 px
  int x0 = (tile & 31) << 2;
  int y0 = (tile >> 5) << 2;
  int x = x0 | (pl & 3);
  int y = y0 | (pl >> 2);
  float px = (float)x + 0.5f, py = (float)y + 0.5f;

  if (t == 0) lcnt = 0;
  if (t < PXB) scnt[t] = 0;
  __syncthreads();

  // ---- phase 1: bbox filter (per tile, 8 gaussians/thread, coalesced) ----
  // Any pixel with alpha >= ALPHA_MIN lies within r = RADIUS_K * s_max of the
  // mean (q >= |d|^2 / s_max^2). Circle-vs-rect on pixel-center rect, with a
  // small margin for fp32 rounding -> conservative (never drops a contributor).
  float rx0 = (float)x0 + 0.5f, rx1 = (float)x0 + 3.5f;
  float ry0 = (float)y0 + 0.5f, ry1 = (float)y0 + 3.5f;
  for (int g = t; g < nG; g += 256) {
    float mx = means[2 * g], my = means[2 * g + 1];
    float smax = __expf(fmaxf(lscales[2 * g], lscales[2 * g + 1]));
    float r = RADIUS_K * smax * 1.01f + 0.05f;
    float cx = fminf(fmaxf(mx, rx0), rx1) - mx;
    float cy = fminf(fmaxf(my, ry0), ry1) - my;
    if (cx * cx + cy * cy <= r * r) {
      int idx = atomicAdd(&lcnt, 1);
      if (idx < LCAP) glist[idx] = g;
    }
  }
  __syncthreads();
  int cnt = min(lcnt, LCAP);

  // ---- phase 2: full params for survivors only (~126 per tile) ----
  for (int i = t; i < cnt; i += 256) {
    int g = glist[i];
    float th = rots[g];
    float s = __sinf(th), c = __cosf(th);
    float ivx = __expf(-2.0f * lscales[2 * g]);
    float ivy = __expf(-2.0f * lscales[2 * g + 1]);
    float a  = c * c * ivx + s * s * ivy;
    float cc = s * s * ivx + c * c * ivy;
    float b2 = 2.0f * (c * s * (ivx - ivy));
    sA[i]  = make_float4(a, b2, cc, means[2 * g]);
    sMy[i] = means[2 * g + 1];
  }
  __syncthreads();

  // ---- phase 3: eval survivors, push alpha >= ALPHA_MIN per pixel ----
  // Lanes with equal ts read the same sA line (16-way broadcast, 4 distinct
  // 16B lines per wave -> conflict-free).
  for (int i = ts; i < cnt; i += TPP) {
    float4 q0 = sA[i];
    float dx = px - q0.w;
    float dy = py - sMy[i];
    float q = fmaf(dx, fmaf(q0.y, dy, q0.x * dx), q0.z * dy * dy);
    float a = __expf(-0.5f * q);
    if (a >= ALPHA_MIN) {
      int idx = atomicAdd(&scnt[pl], 1);
      if (idx < SCAP) sbuf[pl][idx] = make_float2(a, __int_as_float(glist[i]));
    }
  }
  __syncthreads();

  // ---- phase 4: exact top-10 select (2 lanes/pixel) + composite ----
  if (t < 2 * PXB) {
    int p2 = t >> 1, half = t & 1;
    int sc = min(scnt[p2], SCAP);
    float vals[KK];
    int ids[KK];
#pragma unroll
    for (int k = 0; k < KK; ++k) { vals[k] = 0.0f; ids[k] = 0; }
    for (int i = half; i < sc; i += 2) {
      float2 e = sbuf[p2][i];
      float a = e.x;
      int id = __float_as_int(e.y);
      if (beats(a, id, vals[KK - 1], ids[KK - 1])) insert_tb(vals, ids, a, id);
    }
    // combine the two halves over the lane pair
    float ov[KK];
    int oi[KK];
#pragma unroll
    for (int k = 0; k < KK; ++k) {
      ov[k] = __shfl_xor(vals[k], 1);
      oi[k] = __shfl_xor(ids[k], 1);
    }
    if (half == 0) {
#pragma unroll
      for (int k = 0; k < KK; ++k) {
        if (!beats(ov[k], oi[k], vals[KK - 1], ids[KK - 1])) break;
        insert_tb(vals, ids, ov[k], oi[k]);
      }
      int xx = x0 | (p2 & 3);
      int yy = y0 | (p2 >> 2);
      int pp = yy * WW + xx;
      float trans = 1.0f, r = 0.0f, g = 0.0f, b = 0.0f;
#pragma unroll
      for (int k = 0; k < KK; ++k) {
        float a = vals[k];             // sentinel 0.0 contributes nothing
        float w = a * trans;
        int id = ids[k];
        r += w * cols[3 * id + 0];
        g += w * cols[3 * id + 1];
        b += w * cols[3 * id + 2];
        trans *= (1.0f - a);
      }
      out[3 * pp + 0] = r;
      out[3 * pp + 1] = g;
      out[3 * pp + 2] = b;
    }
  }
}

extern "C" void kernel_launch(void* const* d_in, const int* in_sizes, int n_in,
                              void* d_out, int out_size, void* d_ws, size_t ws_size,
                              hipStream_t stream) {
  const float* means   = (const float*)d_in[0];
  const float* rots    = (const float*)d_in[1];
  const float* lscales = (const float*)d_in[2];
  const float* cols    = (const float*)d_in[3];
  float* out = (float*)d_out;
  int nG = in_sizes[1];  // rotations: one per gaussian

  splat_kernel<<<NPX / PXB, 256, 0, stream>>>(means, rots, lscales, cols, nG, out);
}

// Round 5
// 76.014 us; speedup vs baseline: 2.4784x; 1.1086x over previous
//
#include <hip/hip_runtime.h>

#define HH 128
#define WW 128
#define NPX (HH * WW)
#define KK 10
#define PXB 16        // pixels per block (4x4 tile)
#define TPP 16        // threads per pixel
#define LCAP 352      // per-tile gaussian list cap (expected ~110, ~3x margin)
#define JMAX 22       // ceil(LCAP / TPP) — per-thread register alpha cache
#define SCAP 128      // per-pixel survivor cap (expected ~16 after tau gate)
#define SPAD 129      // sbuf row stride (odd -> banks rotate)
#define SMPAD 17      // smax row stride (odd -> conflict-free)
#define ALPHA_MIN 5e-4f
#define RADIUS_K 3.8990f  // sqrt(2*ln(1/ALPHA_MIN))

// Lexicographic (alpha desc, id asc) — exact jax.lax.top_k tie semantics,
// independent of candidate arrival order.
__device__ __forceinline__ bool beats(float a, int ai, float b, int bi) {
  return (a > b) || (a == b && ai < bi);
}

__device__ __forceinline__ void insert_tb(float vals[KK], int ids[KK], float v,
                                          int vi) {
#pragma unroll
  for (int k = 0; k < KK; ++k) {
    bool sw = beats(v, vi, vals[k], ids[k]);
    float tv = vals[k];
    int ti = ids[k];
    vals[k] = sw ? v : tv;
    ids[k]  = sw ? vi : ti;
    v  = sw ? tv : v;
    vi = sw ? ti : vi;
  }
}

__device__ __forceinline__ void bubble_vals10(float vals[KK], float v) {
#pragma unroll
  for (int k = 0; k < KK; ++k) {
    float tv = vals[k];
    bool sw = v > tv;
    vals[k] = sw ? v : tv;
    v = sw ? tv : v;
  }
}

// One block = one 4x4-pixel tile.
__global__ __launch_bounds__(256) void splat_kernel(
    const float* __restrict__ means, const float* __restrict__ rots,
    const float* __restrict__ lscales, const float* __restrict__ cols,
    int nG, float* __restrict__ out) {
  __shared__ float4 sA[LCAP];            // (a, 2b, c, mean_x)
  __shared__ float  sMy[LCAP];
  __shared__ int    glist[LCAP];
  __shared__ float  smax[PXB * SMPAD];   // per-(pixel, thread-slot) max alpha
  __shared__ float  stau[PXB];
  __shared__ float2 sbuf[PXB][SPAD];     // (alpha, id-bits)
  __shared__ int    scnt[PXB];
  __shared__ int    lcnt;

  int t  = threadIdx.x;
  int pl = t & 15;   // pixel within tile
  int ts = t >> 4;   // per-pixel thread slot 0..15
  int tile = blockIdx.x;                 // 32x32 tiles of 4x4 px
  int x0 = (tile & 31) << 2;
  int y0 = (tile >> 5) << 2;
  int x = x0 | (pl & 3);
  int y = y0 | (pl >> 2);
  float px = (float)x + 0.5f, py = (float)y + 0.5f;

  if (t == 0) lcnt = 0;
  if (t < PXB) scnt[t] = 0;
  __syncthreads();

  // ---- phase 1: bbox filter + fused param compute for survivors ----
  // alpha >= ALPHA_MIN implies |d| <= RADIUS_K * s_max (q >= |d|^2/s_max^2).
  // Circle-vs-rect with fp32 margin -> conservative (never drops a contributor).
  const float2* m2 = (const float2*)means;
  const float2* l2 = (const float2*)lscales;
  float rx0 = (float)x0 + 0.5f, rx1 = (float)x0 + 3.5f;
  float ry0 = (float)y0 + 0.5f, ry1 = (float)y0 + 3.5f;
  for (int g = t; g < nG; g += 256) {
    float2 mg = m2[g];
    float2 lg = l2[g];
    float smx = __expf(fmaxf(lg.x, lg.y));
    float r = fmaf(RADIUS_K * 1.01f, smx, 0.05f);
    float cx = fminf(fmaxf(mg.x, rx0), rx1) - mg.x;
    float cy = fminf(fmaxf(mg.y, ry0), ry1) - mg.y;
    if (cx * cx + cy * cy <= r * r) {
      int idx = atomicAdd(&lcnt, 1);
      if (idx < LCAP) {
        float th = rots[g];               // only gathered load
        float s = __sinf(th), c = __cosf(th);
        float ivx = __expf(-2.0f * lg.x);
        float ivy = __expf(-2.0f * lg.y);
        sA[idx] = make_float4(c * c * ivx + s * s * ivy,
                              2.0f * (c * s * (ivx - ivy)),
                              s * s * ivx + c * c * ivy, mg.x);
        sMy[idx] = mg.y;
        glist[idx] = g;
      }
    }
  }
  __syncthreads();
  int cnt = min(lcnt, LCAP);

  // ---- phase 2: eval survivors into registers; per-thread max ----
  // Fully unrolled fixed-trip loop keeps ra[] in VGPRs (no scratch).
  float ra[JMAX];
  float mymax = 0.0f;
#pragma unroll
  for (int j = 0; j < JMAX; ++j) {
    int i = ts + j * TPP;
    float a = 0.0f;
    if (i < cnt) {
      float4 q0 = sA[i];                 // 16-lane broadcast reads
      float dx = px - q0.w;
      float dy = py - sMy[i];
      float q = fmaf(dx, fmaf(q0.y, dy, q0.x * dx), q0.z * dy * dy);
      a = __expf(-0.5f * q);
    }
    ra[j] = a;
    mymax = fmaxf(mymax, a);
  }
  smax[pl * SMPAD + ts] = mymax;
  __syncthreads();

  // ---- phase 2b: per-pixel tau = 10th largest of the 16 thread maxes.
  // Those 16 values are a subset of the pixel's alphas, so tau <= true 10th
  // largest -> gating pushes with alpha >= tau is exact (ties kept).
  // ALPHA_MIN floor perturbs output by <= 10*5e-4 << 2e-2 threshold.
  if (t < PXB) {
    float tv[KK];
#pragma unroll
    for (int k = 0; k < KK; ++k) tv[k] = 0.0f;
#pragma unroll
    for (int j = 0; j < TPP; ++j) bubble_vals10(tv, smax[t * SMPAD + j]);
    stau[t] = fmaxf(tv[KK - 1], ALPHA_MIN);
  }
  __syncthreads();

  // ---- phase 2c: push gated survivors (expected ~16/pixel) ----
  float tau = stau[pl];
#pragma unroll
  for (int j = 0; j < JMAX; ++j) {
    int i = ts + j * TPP;
    float a = ra[j];
    if (a >= tau) {                      // implies i < cnt (else a == 0)
      int idx = atomicAdd(&scnt[pl], 1);
      if (idx < SCAP) sbuf[pl][idx] = make_float2(a, __int_as_float(glist[i]));
    }
  }
  __syncthreads();

  // ---- phase 3: exact top-10 select (2 lanes/pixel) + composite ----
  if (t < 2 * PXB) {
    int p2 = t >> 1, half = t & 1;
    int sc = min(scnt[p2], SCAP);
    float vals[KK];
    int ids[KK];
#pragma unroll
    for (int k = 0; k < KK; ++k) { vals[k] = 0.0f; ids[k] = 0; }
    for (int i = half; i < sc; i += 2) {
      float2 e = sbuf[p2][i];
      float a = e.x;
      int id = __float_as_int(e.y);
      if (beats(a, id, vals[KK - 1], ids[KK - 1])) insert_tb(vals, ids, a, id);
    }
    float ov[KK];
    int oi[KK];
#pragma unroll
    for (int k = 0; k < KK; ++k) {
      ov[k] = __shfl_xor(vals[k], 1);
      oi[k] = __shfl_xor(ids[k], 1);
    }
    if (half == 0) {
#pragma unroll
      for (int k = 0; k < KK; ++k) {
        if (!beats(ov[k], oi[k], vals[KK - 1], ids[KK - 1])) break;
        insert_tb(vals, ids, ov[k], oi[k]);
      }
      int xx = x0 | (p2 & 3);
      int yy = y0 | (p2 >> 2);
      int pp = yy * WW + xx;
      float trans = 1.0f, r = 0.0f, g = 0.0f, b = 0.0f;
#pragma unroll
      for (int k = 0; k < KK; ++k) {
        float a = vals[k];               // sentinel 0.0 contributes nothing
        float w = a * trans;
        int id = ids[k];
        r += w * cols[3 * id + 0];
        g += w * cols[3 * id + 1];
        b += w * cols[3 * id + 2];
        trans *= (1.0f - a);
      }
      out[3 * pp + 0] = r;
      out[3 * pp + 1] = g;
      out[3 * pp + 2] = b;
    }
  }
}

extern "C" void kernel_launch(void* const* d_in, const int* in_sizes, int n_in,
                              void* d_out, int out_size, void* d_ws, size_t ws_size,
                              hipStream_t stream) {
  const float* means   = (const float*)d_in[0];
  const float* rots    = (const float*)d_in[1];
  const float* lscales = (const float*)d_in[2];
  const float* cols    = (const float*)d_in[3];
  float* out = (float*)d_out;
  int nG = in_sizes[1];  // rotations: one per gaussian

  splat_kernel<<<NPX / PXB, 256, 0, stream>>>(means, rots, lscales, cols, nG, out);
}

// Round 6
// 74.186 us; speedup vs baseline: 2.5395x; 1.0247x over previous
//
#include <hip/hip_runtime.h>

#define HH 128
#define WW 128
#define NPX (HH * WW)
#define KK 10
#define PXB 16        // pixels per block (4x4 tile); pixel group = 16 contiguous lanes
#define LCAP 352      // per-tile gaussian list cap (expected ~126)
#define JMAX 22       // LCAP / 16 slots per lane
#define KEYC 6        // per-lane survivor keys (96/pixel cap, expected ~20)
#define SCAP (16 * KEYC)
#define SPAD (SCAP + 1)
#define ALPHA_MIN 5e-4f
#define RADIUS_K 3.8990f  // sqrt(2*ln(1/ALPHA_MIN))

typedef unsigned long long u64;
typedef unsigned int u32;

__device__ __forceinline__ u64 umax64(u64 a, u64 b) { return a > b ? a : b; }

// One block = one 4x4-pixel tile; 4 waves; each pixel owned by 16 contiguous
// lanes of one wave -> all post-filter steps are wave-synchronous (no barriers).
template <int NGC>
__global__ __launch_bounds__(256) void splat_kernel(
    const float* __restrict__ means, const float* __restrict__ rots,
    const float* __restrict__ lscales, const float* __restrict__ cols,
    int nG_rt, float* __restrict__ out) {
  const int nG = NGC > 0 ? NGC : nG_rt;
  __shared__ float4 sA[LCAP];           // (a, 2b, c, mean_x)
  __shared__ float  sMy[LCAP];
  __shared__ int    glist[LCAP];
  __shared__ float2 sbuf[PXB][SPAD];    // (alpha, id-bits)
  __shared__ int    lcnt;

  int t = threadIdx.x;
  int lane = t & 63;
  int pl  = t >> 4;   // pixel within tile (wave w owns pixels 4w..4w+3)
  int tsl = t & 15;   // lane within pixel group
  int tile = blockIdx.x;
  int x0 = (tile & 31) << 2, y0 = (tile >> 5) << 2;
  int x = x0 | (pl & 3), y = y0 | (pl >> 2);
  float px = (float)x + 0.5f, py = (float)y + 0.5f;

  if (t == 0) lcnt = 0;
  __syncthreads();

  // ---- phase 1: conservative bbox filter + fused params, ballot-aggregated ----
  // alpha >= ALPHA_MIN implies |d| <= RADIUS_K * s_max; circle-vs-rect with
  // fp32 margin never drops a contributor.
  const float2* m2 = (const float2*)means;
  const float2* l2 = (const float2*)lscales;
  float rx0 = (float)x0 + 0.5f, rx1 = (float)x0 + 3.5f;
  float ry0 = (float)y0 + 0.5f, ry1 = (float)y0 + 3.5f;
  for (int g = t; g < nG; g += 256) {
    float2 mg = m2[g];
    float2 lg = l2[g];
    float smx = __expf(fmaxf(lg.x, lg.y));
    float r = fmaf(RADIUS_K * 1.01f, smx, 0.05f);
    float cx = fminf(fmaxf(mg.x, rx0), rx1) - mg.x;
    float cy = fminf(fmaxf(mg.y, ry0), ry1) - mg.y;
    bool hit = (cx * cx + cy * cy <= r * r);
    u64 mask = __ballot(hit);
    if (mask) {                                   // wave-uniform
      int leader = __ffsll((unsigned long long)mask) - 1;
      int base;
      if (lane == leader) base = atomicAdd(&lcnt, __popcll(mask));
      base = __shfl(base, leader);
      if (hit) {
        int idx = base + __popcll(mask & ((1ull << lane) - 1ull));
        if (idx < LCAP) {
          float th = rots[g];                     // only gathered load
          float s = __sinf(th), c = __cosf(th);
          float ivx = __expf(-2.0f * lg.x);
          float ivy = __expf(-2.0f * lg.y);
          sA[idx] = make_float4(c * c * ivx + s * s * ivy,
                                2.0f * (c * s * (ivx - ivy)),
                                s * s * ivx + c * c * ivy, mg.x);
          sMy[idx] = mg.y;
          glist[idx] = g;
        }
      }
    }
  }
  __syncthreads();                                // last barrier
  int cnt = min(lcnt, LCAP);

  // ---- phase 2: eval into registers (16 consecutive float4 per group:
  // 2-way bank aliasing -> free) ----
  float ra[JMAX];
  float mymax = 0.0f;
#pragma unroll
  for (int j = 0; j < JMAX; ++j) {
    int i = tsl + j * 16;
    float a = 0.0f;
    if (i < cnt) {
      float4 q0 = sA[i];
      float dx = px - q0.w, dy = py - sMy[i];
      float q = fmaf(dx, fmaf(q0.y, dy, q0.x * dx), q0.z * dy * dy);
      a = __expf(-0.5f * q);
    }
    ra[j] = a;
    mymax = fmaxf(mymax, a);
  }

  // ---- tau = 10th largest of the 16 lane maxes (distinct lanes -> distinct
  // candidates -> >=10 alphas >= tau -> sound lower bound on the pixel's true
  // 10th; ties kept via >=). ALPHA_MIN floor perturbs <= 10*5e-4 << 2e-2.
  float tv[KK];
#pragma unroll
  for (int k = 0; k < KK; ++k) tv[k] = 0.0f;
#pragma unroll
  for (int i = 0; i < 16; ++i) {
    float v = __shfl(mymax, i, 16);
#pragma unroll
    for (int k = 0; k < KK; ++k) {
      float tvk = tv[k];
      bool sw = v > tvk;
      tv[k] = sw ? v : tvk;
      v = sw ? tvk : v;
    }
  }
  float tau = fmaxf(tv[KK - 1], ALPHA_MIN);

  // ---- gated push via ballot compaction (no atomics, same-wave LDS) ----
  int cpx = 0;                 // group-uniform running count
  int grp = lane >> 4;
#pragma unroll
  for (int j = 0; j < JMAX; ++j) {
    bool s = ra[j] >= tau;     // implies slot valid (else ra==0 < tau)
    u64 mask = __ballot(s);
    u32 sub = (u32)((mask >> (grp * 16)) & 0xFFFFull);
    if (s) {
      int idx = cpx + __popc(sub & ((1u << tsl) - 1u));
      if (idx < SCAP)
        sbuf[pl][idx] = make_float2(ra[j], __int_as_float(glist[tsl + j * 16]));
    }
    cpx += __popc(sub);
  }
  int scp = min(cpx, SCAP);

  // ---- load survivors as sortable keys: (alpha_bits<<32) | ~id ----
  // key desc == alpha desc, id asc == exact jax.lax.top_k order. Keys unique.
  u64 keys[KEYC];
#pragma unroll
  for (int c = 0; c < KEYC; ++c) {
    int i = tsl + c * 16;
    u64 kk = 0;
    if (i < scp) {
      float2 e = sbuf[pl][i];   // written by this wave; DS ops are in-order
      kk = ((u64)__float_as_uint(e.x) << 32) | (u32)(~(u32)__float_as_int(e.y));
    }
    keys[c] = kk;
  }

  // ---- top-10 by repeated 16-lane max extraction; lane r latches winner r ----
  float my_alpha = 0.0f;
  int my_id = 0;
#pragma unroll
  for (int r = 0; r < KK; ++r) {
    u64 m = keys[0];
#pragma unroll
    for (int c = 1; c < KEYC; ++c) m = umax64(m, keys[c]);
#pragma unroll
    for (int d = 1; d < 16; d <<= 1)
      m = umax64(m, (u64)__shfl_xor((unsigned long long)m, d));
#pragma unroll
    for (int c = 0; c < KEYC; ++c)
      if (keys[c] == m) keys[c] = 0;   // unique winner; no-op when m==0
    if (tsl == r && m != 0) {
      my_alpha = __uint_as_float((u32)(m >> 32));
      my_id = (int)(~(u32)m);
    }
  }

  // ---- composite: exclusive prefix product of (1-alpha) + butterfly sum ----
  float T = 1.0f - my_alpha;           // lanes >= #winners: alpha=0 -> om=1
#pragma unroll
  for (int d = 1; d < 16; d <<= 1) {
    float u = __shfl_up(T, d, 16);
    if (tsl >= d) T *= u;
  }
  float ex = __shfl_up(T, 1, 16);
  if (tsl == 0) ex = 1.0f;
  float w = my_alpha * ex;
  float cr = 0.0f, cg = 0.0f, cb = 0.0f;
  if (my_alpha > 0.0f) {
    cr = w * cols[3 * my_id + 0];
    cg = w * cols[3 * my_id + 1];
    cb = w * cols[3 * my_id + 2];
  }
#pragma unroll
  for (int d = 1; d < 16; d <<= 1) {
    cr += __shfl_xor(cr, d);
    cg += __shfl_xor(cg, d);
    cb += __shfl_xor(cb, d);
  }
  int p = y * WW + x;
  if (tsl < 3) out[3 * p + tsl] = (tsl == 0) ? cr : ((tsl == 1) ? cg : cb);
}

extern "C" void kernel_launch(void* const* d_in, const int* in_sizes, int n_in,
                              void* d_out, int out_size, void* d_ws, size_t ws_size,
                              hipStream_t stream) {
  const float* means   = (const float*)d_in[0];
  const float* rots    = (const float*)d_in[1];
  const float* lscales = (const float*)d_in[2];
  const float* cols    = (const float*)d_in[3];
  float* out = (float*)d_out;
  int nG = in_sizes[1];  // rotations: one per gaussian

  if (nG == 2048) {
    splat_kernel<2048><<<NPX / PXB, 256, 0, stream>>>(means, rots, lscales,
                                                      cols, nG, out);
  } else {
    splat_kernel<0><<<NPX / PXB, 256, 0, stream>>>(means, rots, lscales,
                                                   cols, nG, out);
  }
}